// Round 1
// baseline (5697.007 us; speedup 1.0000x reference)
//
#include <hip/hip_runtime.h>
#include <math.h>

#define B_    4096
#define N_    3400
#define D1_   2048
#define D2_   1024
#define E_    10
#define C_    17
#define TOPK_ 20
#define TAU_  10.0f

__device__ inline float wsum64(float v){
  #pragma unroll
  for (int m = 1; m < 64; m <<= 1) v += __shfl_xor(v, m);
  return v;
}

// --- row 1/max(||x||,eps) for [R][D] ---
__global__ __launch_bounds__(256)
void rownorm_inv(const float* __restrict__ X, int D, float* __restrict__ rinv){
  int r = blockIdx.x, t = threadIdx.x;
  const float4* x4 = reinterpret_cast<const float4*>(X + (long)r * D);
  float ss = 0.f;
  for (int i = t; i < (D >> 2); i += 256){
    float4 v = x4[i];
    ss += v.x*v.x + v.y*v.y + v.z*v.z + v.w*v.w;
  }
  __shared__ float red[256];
  red[t] = ss; __syncthreads();
  for (int s = 128; s; s >>= 1){ if (t < s) red[t] += red[t + s]; __syncthreads(); }
  if (t == 0) rinv[r] = 1.f / fmaxf(sqrtf(red[0]), 1e-12f);
}

__global__ void zero_cnt(float* cnt){ if (threadIdx.x < C_) cnt[threadIdx.x] = 0.f; }

// labels are one-hot: record class y[n], count per class
__global__ __launch_bounds__(256)
void labelprep(const float* __restrict__ labels, int* __restrict__ y, float* __restrict__ cnt){
  int n = blockIdx.x * 256 + threadIdx.x;
  if (n >= N_) return;
  int c = 0;
  #pragma unroll
  for (int cc = 0; cc < C_; ++cc) if (labels[n * C_ + cc] > 0.5f) c = cc;
  y[n] = c;
  atomicAdd(&cnt[c], 1.0f);
}

// Out[e][m][n] = post(colscale,rowscale,bias)( sum_k A[m,k]*kscale[e,k]*B[n,k] )
__global__ __launch_bounds__(256)
void gemm64(const float* __restrict__ A, int lda,
            const float* __restrict__ Bm, int ldb,
            float* __restrict__ Out, long out_estride, int ldo,
            int M, int N, int K,
            const float* __restrict__ kscale, int kscale_estride,
            const float* __restrict__ rowscale,
            const float* __restrict__ colscale, int colscale_estride,
            const float* __restrict__ colbias, int colbias_estride)
{
  __shared__ float As[16][68];
  __shared__ float Bs[16][68];
  const int e  = blockIdx.z;
  const int m0 = blockIdx.y * 64, n0 = blockIdx.x * 64;
  const int t  = threadIdx.x;
  const int lr = t >> 2;          // 0..63: tile row loaded by this thread
  const int lk = (t & 3) << 2;    // 0,4,8,12: k sub-offset
  const int ty4 = (t >> 4) << 2;  // micro-tile row base
  const int tx4 = (t & 15) << 2;  // micro-tile col base
  const float* ks = kscale ? kscale + (long)e * kscale_estride : nullptr;
  const bool aok = (m0 + lr) < M;
  const bool bok = (n0 + lr) < N;
  const float* ap = A  + (long)(m0 + lr) * lda + lk;
  const float* bp = Bm + (long)(n0 + lr) * ldb + lk;
  float acc[4][4] = {{0.f}};
  for (int k0 = 0; k0 < K; k0 += 16){
    float4 av = make_float4(0,0,0,0), bv = make_float4(0,0,0,0);
    if (aok) av = *reinterpret_cast<const float4*>(ap + k0);
    if (bok) bv = *reinterpret_cast<const float4*>(bp + k0);
    if (ks){
      float4 kv = *reinterpret_cast<const float4*>(ks + k0 + lk);
      av.x *= kv.x; av.y *= kv.y; av.z *= kv.z; av.w *= kv.w;
    }
    As[lk+0][lr] = av.x; As[lk+1][lr] = av.y; As[lk+2][lr] = av.z; As[lk+3][lr] = av.w;
    Bs[lk+0][lr] = bv.x; Bs[lk+1][lr] = bv.y; Bs[lk+2][lr] = bv.z; Bs[lk+3][lr] = bv.w;
    __syncthreads();
    #pragma unroll
    for (int kk = 0; kk < 16; ++kk){
      float4 a = *reinterpret_cast<const float4*>(&As[kk][ty4]);
      float4 b = *reinterpret_cast<const float4*>(&Bs[kk][tx4]);
      float aa[4] = {a.x, a.y, a.z, a.w};
      float bb[4] = {b.x, b.y, b.z, b.w};
      #pragma unroll
      for (int i = 0; i < 4; ++i)
        #pragma unroll
        for (int j = 0; j < 4; ++j)
          acc[i][j] += aa[i] * bb[j];
    }
    __syncthreads();
  }
  const float* cs = colscale ? colscale + (long)e * colscale_estride : nullptr;
  const float* cb = colbias  ? colbias  + (long)e * colbias_estride  : nullptr;
  float* op = Out + (long)e * out_estride;
  #pragma unroll
  for (int i = 0; i < 4; ++i){
    int m = m0 + ty4 + i;
    if (m >= M) continue;
    float rs = rowscale ? rowscale[m] : 1.f;
    #pragma unroll
    for (int j = 0; j < 4; ++j){
      int n = n0 + tx4 + j;
      if (n >= N) continue;
      float v = acc[i][j] * rs;
      if (cs) v *= cs[n];
      if (cb) v += cb[n];
      op[(long)m * ldo + n] = v;
    }
  }
}

// top-20 (by value desc, tie -> lower index) per row of scores[B_][N_]
__global__ __launch_bounds__(256)
void topk20(const float* __restrict__ scores, int* __restrict__ idx){
  __shared__ float v[N_];
  __shared__ float rv[256];
  __shared__ int   ri[256];
  const int b = blockIdx.x, t = threadIdx.x;
  const float* row = scores + (long)b * N_;
  for (int i = t; i < N_; i += 256) v[i] = row[i];
  __syncthreads();
  for (int it = 0; it < TOPK_; ++it){
    float bv = -3.0e38f; int bi = 0x7fffffff;
    for (int i = t; i < N_; i += 256){
      float x = v[i];
      if (x > bv){ bv = x; bi = i; }
    }
    rv[t] = bv; ri[t] = bi; __syncthreads();
    for (int s = 128; s; s >>= 1){
      if (t < s){
        float ov = rv[t + s]; int oi = ri[t + s];
        if (ov > rv[t] || (ov == rv[t] && oi < ri[t])){ rv[t] = ov; ri[t] = oi; }
      }
      __syncthreads();
    }
    if (t == 0){ idx[b * TOPK_ + it] = ri[0]; v[ri[0]] = -3.0e38f; }
    __syncthreads();
  }
}

// partial centroids: part[s][e][c][o] = sum_{n in slice s, y[n]=c} mlps[e][n][o]/(cnt_c+eps)
__global__ __launch_bounds__(256)
void centroid_part(const float* __restrict__ mlps, const int* __restrict__ y,
                   const float* __restrict__ cnt, float* __restrict__ part){
  __shared__ float acc[C_ * 256];
  __shared__ float winv[C_];
  const int t  = threadIdx.x;
  const int ob = blockIdx.x * 256;
  const int e  = blockIdx.y;
  const int s  = blockIdx.z;
  #pragma unroll
  for (int c = 0; c < C_; ++c) acc[c * 256 + t] = 0.f;
  if (t < C_) winv[t] = 1.f / (cnt[t] + 1e-12f);
  __syncthreads();
  const int n0 = s * 425, n1 = n0 + 425;   // 8*425 == 3400
  for (int n = n0; n < n1; ++n){
    int c = y[n];
    float v = mlps[((long)e * N_ + n) * D2_ + ob + t];
    acc[c * 256 + t] += winv[c] * v;
  }
  #pragma unroll
  for (int c = 0; c < C_; ++c)
    part[(((long)s * E_ + e) * C_ + c) * D2_ + ob + t] = acc[c * 256 + t];
}

__global__ __launch_bounds__(256)
void centroid_reduce(const float* __restrict__ part, float* __restrict__ cent){
  int i = blockIdx.x * 256 + threadIdx.x;
  if (i >= E_ * C_ * D2_) return;
  float s = 0.f;
  #pragma unroll
  for (int k = 0; k < 8; ++k) s += part[(long)k * E_ * C_ * D2_ + i];
  cent[i] = s;
}

__global__ __launch_bounds__(256)
void rownorm_inplace(float* __restrict__ X, int D){
  int r = blockIdx.x, t = threadIdx.x;
  float4* x4 = reinterpret_cast<float4*>(X + (long)r * D);
  float ss = 0.f;
  for (int i = t; i < (D >> 2); i += 256){
    float4 v = x4[i];
    ss += v.x*v.x + v.y*v.y + v.z*v.z + v.w*v.w;
  }
  __shared__ float red[256];
  red[t] = ss; __syncthreads();
  for (int s2 = 128; s2; s2 >>= 1){ if (t < s2) red[t] += red[t + s2]; __syncthreads(); }
  float rinv = 1.f / fmaxf(sqrtf(red[0]), 1e-12f);
  for (int i = t; i < (D >> 2); i += 256){
    float4 v = x4[i];
    v.x *= rinv; v.y *= rinv; v.z *= rinv; v.w *= rinv;
    x4[i] = v;
  }
}

// per (e,row): 17 cosine dots with cn; mode 1 -> softmax (soft), mode 0 -> TAU*cos (logits)
__global__ __launch_bounds__(64)
void ens_dot(const float* __restrict__ mlp, const float* __restrict__ cn,
             float* __restrict__ out, int mlp_rows, int out_M, int out_rowoff, int mode){
  const int row = blockIdx.x, e = blockIdx.y, l = threadIdx.x;
  const float4* r4 = reinterpret_cast<const float4*>(mlp + ((long)e * mlp_rows + row) * D2_);
  float4 r[4];
  #pragma unroll
  for (int j = 0; j < 4; ++j) r[j] = r4[j * 64 + l];
  float ss = 0.f;
  #pragma unroll
  for (int j = 0; j < 4; ++j) ss += r[j].x*r[j].x + r[j].y*r[j].y + r[j].z*r[j].z + r[j].w*r[j].w;
  ss = wsum64(ss);
  float rinv = 1.f / fmaxf(sqrtf(ss), 1e-12f);
  float tv[C_];
  #pragma unroll
  for (int c = 0; c < C_; ++c){
    const float4* c4 = reinterpret_cast<const float4*>(cn + ((long)e * C_ + c) * D2_);
    float p = 0.f;
    #pragma unroll
    for (int j = 0; j < 4; ++j){
      float4 cv = c4[j * 64 + l];
      p += r[j].x*cv.x + r[j].y*cv.y + r[j].z*cv.z + r[j].w*cv.w;
    }
    tv[c] = wsum64(p) * rinv * TAU_;
  }
  long obase = ((long)e * out_M + out_rowoff + row) * C_;
  if (mode == 0){
    if (l == 0){
      #pragma unroll
      for (int c = 0; c < C_; ++c) out[obase + c] = tv[c];
    }
  } else {
    float m = tv[0];
    #pragma unroll
    for (int c = 1; c < C_; ++c) m = fmaxf(m, tv[c]);
    float p[C_]; float sum = 0.f;
    #pragma unroll
    for (int c = 0; c < C_; ++c){ p[c] = expf(tv[c] - m); sum += p[c]; }
    float is = 1.f / sum;
    if (l == 0){
      #pragma unroll
      for (int c = 0; c < C_; ++c) out[obase + c] = p[c] * is;
    }
  }
}

// outputs[b][c] = mean_e ( sum_{k<20} soft[e][idx_k][c] / (sum_c .. + eps) )
__global__ __launch_bounds__(256)
void outputs_k(const float* __restrict__ soft, const int* __restrict__ idx, float* __restrict__ out){
  const int lane = threadIdx.x & 63;
  const int b = blockIdx.x * 4 + (threadIdx.x >> 6);
  const int* id = idx + b * TOPK_;
  float o = 0.f;
  for (int e = 0; e < E_; ++e){
    float S = 0.f;
    const float* se = soft + (long)e * N_ * C_;
    #pragma unroll
    for (int k = 0; k < TOPK_; ++k){
      int n = id[k];
      if (lane < C_) S += se[(long)n * C_ + lane];
    }
    float tot = wsum64(S);
    o += S / (tot + 1e-12f);
  }
  if (lane < C_) out[(long)b * C_ + lane] = o * (1.f / E_);
}

extern "C" void kernel_launch(void* const* d_in, const int* in_sizes, int n_in,
                              void* d_out, int out_size, void* d_ws, size_t ws_size,
                              hipStream_t stream){
  const float* z        = (const float*)d_in[0];
  const float* supports = (const float*)d_in[1];
  const float* labels   = (const float*)d_in[2];
  const float* weight   = (const float*)d_in[3];
  const float* alpha    = (const float*)d_in[4];
  const float* gamma    = (const float*)d_in[5];
  const float* bias     = (const float*)d_in[6];
  float* out = (float*)d_out;

  char* w = (char*)d_ws;
  size_t off = 0;
  auto alloc = [&](size_t bytes)->char*{
    char* p = w + off;
    off = (off + bytes + 255) & ~(size_t)255;
    return p;
  };
  float* zinv   = (float*)alloc((size_t)B_ * 4);
  float* sinv   = (float*)alloc((size_t)N_ * 4);
  float* cnt    = (float*)alloc((size_t)C_ * 4);
  int*   y      = (int*)  alloc((size_t)N_ * 4);
  int*   idx    = (int*)  alloc((size_t)B_ * TOPK_ * 4);
  float* scores = (float*)alloc((size_t)B_ * N_ * 4);
  float* mlps   = (float*)alloc((size_t)E_ * N_ * D2_ * 4);
  float* part   = (float*)alloc((size_t)8 * E_ * C_ * D2_ * 4);
  float* cent   = (float*)alloc((size_t)E_ * C_ * D2_ * 4);
  float* soft   = (float*)alloc((size_t)E_ * N_ * C_ * 4);
  float* mlpz   = (float*)alloc((size_t)E_ * 1024 * D2_ * 4);
  (void)ws_size; (void)in_sizes; (void)n_in; (void)out_size;

  // row norms of z / supports (applied as post-scales in the scores GEMM)
  rownorm_inv<<<B_, 256, 0, stream>>>(z, D1_, zinv);
  rownorm_inv<<<N_, 256, 0, stream>>>(supports, D1_, sinv);

  // label prep
  zero_cnt<<<1, 32, 0, stream>>>(cnt);
  labelprep<<<(N_ + 255) / 256, 256, 0, stream>>>(labels, y, cnt);

  // cosine scores (fp32 for exact-enough top-k selection) + top-20
  gemm64<<<dim3((N_ + 63) / 64, (B_ + 63) / 64, 1), 256, 0, stream>>>(
      z, D1_, supports, D1_, scores, 0, N_, B_, N_, D1_,
      nullptr, 0, zinv, sinv, 0, nullptr, 0);
  topk20<<<B_, 256, 0, stream>>>(scores, idx);

  // mlp_s = gamma*( (supports*alpha_e) @ W^T ) + bias   for each e
  gemm64<<<dim3(D2_ / 64, (N_ + 63) / 64, E_), 256, 0, stream>>>(
      supports, D1_, weight, D1_, mlps, (long)N_ * D2_, D2_, N_, D2_, D1_,
      alpha, D1_, nullptr, gamma, D2_, bias, D2_);

  // centroids (one-hot labels -> class-bucketed weighted sums), then L2-normalize rows
  centroid_part<<<dim3(D2_ / 256, E_, 8), 256, 0, stream>>>(mlps, y, cnt, part);
  centroid_reduce<<<(E_ * C_ * D2_ + 255) / 256, 256, 0, stream>>>(part, cent);
  rownorm_inplace<<<E_ * C_, 256, 0, stream>>>(cent, D2_);

  // soft = softmax(TAU * cos(mlp_s, cent))
  ens_dot<<<dim3(N_, E_), 64, 0, stream>>>(mlps, cent, soft, N_, N_, 0, 1);

  // outputs
  outputs_k<<<B_ / 4, 256, 0, stream>>>(soft, idx, out);

  // logits, chunked over z rows (reuse mlpz buffer)
  float* logits = out + (size_t)B_ * C_;
  for (int ch = 0; ch < 4; ++ch){
    gemm64<<<dim3(D2_ / 64, 1024 / 64, E_), 256, 0, stream>>>(
        z + (size_t)ch * 1024 * D1_, D1_, weight, D1_, mlpz, (long)1024 * D2_, D2_,
        1024, D2_, D1_, alpha, D1_, nullptr, gamma, D2_, bias, D2_);
    ens_dot<<<dim3(1024, E_), 64, 0, stream>>>(mlpz, cent, logits, 1024, B_, ch * 1024, 0);
  }
}

// Round 2
// 2216.574 us; speedup vs baseline: 2.5702x; 2.5702x over previous
//
#include <hip/hip_runtime.h>
#include <math.h>

#define B_    4096
#define N_    3400
#define D1_   2048
#define D2_   1024
#define E_    10
#define C_    17
#define TOPK_ 20
#define TAU_  10.0f

typedef __bf16 bf16x8 __attribute__((ext_vector_type(8)));
typedef float  f32x4  __attribute__((ext_vector_type(4)));

__device__ inline float wsum64(float v){
  #pragma unroll
  for (int m = 1; m < 64; m <<= 1) v += __shfl_xor(v, m);
  return v;
}

__device__ inline unsigned int f2bf_pair(float lo, float hi){
  unsigned int ulo = __float_as_uint(lo);
  unsigned int uhi = __float_as_uint(hi);
  ulo = ulo + 0x7fffu + ((ulo >> 16) & 1u);
  uhi = uhi + 0x7fffu + ((uhi >> 16) & 1u);
  return (ulo >> 16) | (uhi & 0xffff0000u);
}

// --- row 1/max(||x||,eps) for [R][D] ---
__global__ __launch_bounds__(256)
void rownorm_inv(const float* __restrict__ X, int D, float* __restrict__ rinv){
  int r = blockIdx.x, t = threadIdx.x;
  const float4* x4 = reinterpret_cast<const float4*>(X + (long)r * D);
  float ss = 0.f;
  for (int i = t; i < (D >> 2); i += 256){
    float4 v = x4[i];
    ss += v.x*v.x + v.y*v.y + v.z*v.z + v.w*v.w;
  }
  __shared__ float red[256];
  red[t] = ss; __syncthreads();
  for (int s = 128; s; s >>= 1){ if (t < s) red[t] += red[t + s]; __syncthreads(); }
  if (t == 0) rinv[r] = 1.f / fmaxf(sqrtf(red[0]), 1e-12f);
}

__global__ void zero_cnt(float* cnt){ if (threadIdx.x < C_) cnt[threadIdx.x] = 0.f; }

__global__ __launch_bounds__(256)
void labelprep(const float* __restrict__ labels, int* __restrict__ y, float* __restrict__ cnt){
  int n = blockIdx.x * 256 + threadIdx.x;
  if (n >= N_) return;
  int c = 0;
  #pragma unroll
  for (int cc = 0; cc < C_; ++cc) if (labels[n * C_ + cc] > 0.5f) c = cc;
  y[n] = c;
  atomicAdd(&cnt[c], 1.0f);
}

// fp32 vector GEMM (kept ONLY for the cosine-score matrix feeding top-k:
// bf16 would flip rank-20/21 neighbors whose gap ~4e-4)
__global__ __launch_bounds__(256)
void gemm64(const float* __restrict__ A, int lda,
            const float* __restrict__ Bm, int ldb,
            float* __restrict__ Out, long out_estride, int ldo,
            int M, int N, int K,
            const float* __restrict__ rowscale,
            const float* __restrict__ colscale)
{
  __shared__ float As[16][68];
  __shared__ float Bs[16][68];
  const int m0 = blockIdx.y * 64, n0 = blockIdx.x * 64;
  const int t  = threadIdx.x;
  const int lr = t >> 2;
  const int lk = (t & 3) << 2;
  const int ty4 = (t >> 4) << 2;
  const int tx4 = (t & 15) << 2;
  const bool aok = (m0 + lr) < M;
  const bool bok = (n0 + lr) < N;
  const float* ap = A  + (long)(m0 + lr) * lda + lk;
  const float* bp = Bm + (long)(n0 + lr) * ldb + lk;
  float acc[4][4] = {{0.f}};
  for (int k0 = 0; k0 < K; k0 += 16){
    float4 av = make_float4(0,0,0,0), bv = make_float4(0,0,0,0);
    if (aok) av = *reinterpret_cast<const float4*>(ap + k0);
    if (bok) bv = *reinterpret_cast<const float4*>(bp + k0);
    As[lk+0][lr] = av.x; As[lk+1][lr] = av.y; As[lk+2][lr] = av.z; As[lk+3][lr] = av.w;
    Bs[lk+0][lr] = bv.x; Bs[lk+1][lr] = bv.y; Bs[lk+2][lr] = bv.z; Bs[lk+3][lr] = bv.w;
    __syncthreads();
    #pragma unroll
    for (int kk = 0; kk < 16; ++kk){
      float4 a = *reinterpret_cast<const float4*>(&As[kk][ty4]);
      float4 b = *reinterpret_cast<const float4*>(&Bs[kk][tx4]);
      float aa[4] = {a.x, a.y, a.z, a.w};
      float bb[4] = {b.x, b.y, b.z, b.w};
      #pragma unroll
      for (int i = 0; i < 4; ++i)
        #pragma unroll
        for (int j = 0; j < 4; ++j)
          acc[i][j] += aa[i] * bb[j];
    }
    __syncthreads();
  }
  float* op = Out;
  #pragma unroll
  for (int i = 0; i < 4; ++i){
    int m = m0 + ty4 + i;
    if (m >= M) continue;
    float rs = rowscale ? rowscale[m] : 1.f;
    #pragma unroll
    for (int j = 0; j < 4; ++j){
      int n = n0 + tx4 + j;
      if (n >= N) continue;
      float v = acc[i][j] * rs;
      if (colscale) v *= colscale[n];
      op[(long)m * ldo + n] = v;
    }
  }
}

// MFMA bf16 GEMM: Out[e][m][n] = gamma[e][n]*( sum_k A[m,k]*alpha[e,k]*W[n,k] ) + bias[e][n]
// 128x128 tile, BK=32, 4 waves (2x2), fragment-permuted LDS (lane l frag @ subtile + l*16B)
__global__ __launch_bounds__(256)
void mfma_mlp(const float* __restrict__ A,
              const float* __restrict__ W,
              const float* __restrict__ alpha,
              const float* __restrict__ gamma,
              const float* __restrict__ bias,
              float* __restrict__ Out, long out_estride, int M)
{
  __shared__ unsigned short Alds[128 * 32];   // 8 KB, fragment layout
  __shared__ unsigned short Blds[128 * 32];   // 8 KB
  const int e  = blockIdx.z;
  const int n0 = blockIdx.x * 128;
  const int m0 = blockIdx.y * 128;
  const int t  = threadIdx.x;
  const int lane = t & 63;
  const int w  = t >> 6;
  const int wr = w >> 1, wc = w & 1;

  // staging: thread t loads row (t>>1), k-half (t&1)*16 (16 consecutive fp32)
  const int srow = t >> 1;
  const int skh  = (t & 1) * 16;
  const bool arowok = (m0 + srow) < M;
  const float* ap  = A + (long)(m0 + srow) * D1_ + skh;
  const float* bp  = W + (long)(n0 + srow) * D1_ + skh;
  const float* ksp = alpha + (long)e * D1_ + skh;
  // ushort offsets of the two fragment slots this thread fills
  const unsigned sub = (srow >> 4) * 512;
  const unsigned sl0 = sub + (((skh >> 3) + 0) * 16 + (srow & 15)) * 8;
  const unsigned sl1 = sub + (((skh >> 3) + 1) * 16 + (srow & 15)) * 8;

  f32x4 acc[4][4];
  #pragma unroll
  for (int i = 0; i < 4; ++i)
    #pragma unroll
    for (int j = 0; j < 4; ++j)
      acc[i][j] = (f32x4){0.f, 0.f, 0.f, 0.f};

  for (int k0 = 0; k0 < D1_; k0 += 32){
    float4 av0 = make_float4(0,0,0,0), av1 = av0, av2 = av0, av3 = av0;
    if (arowok){
      const float4* a4 = reinterpret_cast<const float4*>(ap + k0);
      av0 = a4[0]; av1 = a4[1]; av2 = a4[2]; av3 = a4[3];
    }
    const float4* k4 = reinterpret_cast<const float4*>(ksp + k0);
    float4 kv0 = k4[0], kv1 = k4[1], kv2 = k4[2], kv3 = k4[3];
    av0.x*=kv0.x; av0.y*=kv0.y; av0.z*=kv0.z; av0.w*=kv0.w;
    av1.x*=kv1.x; av1.y*=kv1.y; av1.z*=kv1.z; av1.w*=kv1.w;
    av2.x*=kv2.x; av2.y*=kv2.y; av2.z*=kv2.z; av2.w*=kv2.w;
    av3.x*=kv3.x; av3.y*=kv3.y; av3.z*=kv3.z; av3.w*=kv3.w;
    const float4* b4 = reinterpret_cast<const float4*>(bp + k0);
    float4 bv0 = b4[0], bv1 = b4[1], bv2 = b4[2], bv3 = b4[3];

    __syncthreads();   // previous iteration's frag reads complete
    *reinterpret_cast<int4*>(&Alds[sl0]) =
      make_int4(f2bf_pair(av0.x,av0.y), f2bf_pair(av0.z,av0.w),
                f2bf_pair(av1.x,av1.y), f2bf_pair(av1.z,av1.w));
    *reinterpret_cast<int4*>(&Alds[sl1]) =
      make_int4(f2bf_pair(av2.x,av2.y), f2bf_pair(av2.z,av2.w),
                f2bf_pair(av3.x,av3.y), f2bf_pair(av3.z,av3.w));
    *reinterpret_cast<int4*>(&Blds[sl0]) =
      make_int4(f2bf_pair(bv0.x,bv0.y), f2bf_pair(bv0.z,bv0.w),
                f2bf_pair(bv1.x,bv1.y), f2bf_pair(bv1.z,bv1.w));
    *reinterpret_cast<int4*>(&Blds[sl1]) =
      make_int4(f2bf_pair(bv2.x,bv2.y), f2bf_pair(bv2.z,bv2.w),
                f2bf_pair(bv3.x,bv3.y), f2bf_pair(bv3.z,bv3.w));
    __syncthreads();

    bf16x8 af[4], bf[4];
    #pragma unroll
    for (int i = 0; i < 4; ++i)
      af[i] = *reinterpret_cast<const bf16x8*>(&Alds[(wr*4 + i) * 512 + lane * 8]);
    #pragma unroll
    for (int j = 0; j < 4; ++j)
      bf[j] = *reinterpret_cast<const bf16x8*>(&Blds[(wc*4 + j) * 512 + lane * 8]);
    #pragma unroll
    for (int i = 0; i < 4; ++i)
      #pragma unroll
      for (int j = 0; j < 4; ++j)
        acc[i][j] = __builtin_amdgcn_mfma_f32_16x16x32_bf16(af[i], bf[j], acc[i][j], 0, 0, 0);
  }

  const float* cs = gamma + (long)e * D2_;
  const float* cb = bias  + (long)e * D2_;
  float* op = Out + (long)e * out_estride;
  const int mb = m0 + wr * 64 + (lane >> 4) * 4;
  const int nb = n0 + wc * 64 + (lane & 15);
  #pragma unroll
  for (int i = 0; i < 4; ++i){
    #pragma unroll
    for (int j = 0; j < 4; ++j){
      int n = nb + j * 16;
      float g = cs[n], o = cb[n];
      #pragma unroll
      for (int r = 0; r < 4; ++r){
        int m = mb + i * 16 + r;
        if (m < M) op[(long)m * D2_ + n] = acc[i][j][r] * g + o;
      }
    }
  }
}

// top-20 (value desc, tie -> lower index) per row of scores[B_][N_]
__global__ __launch_bounds__(256)
void topk20(const float* __restrict__ scores, int* __restrict__ idx){
  __shared__ float v[N_];
  __shared__ float rv[256];
  __shared__ int   ri[256];
  const int b = blockIdx.x, t = threadIdx.x;
  const float* row = scores + (long)b * N_;
  for (int i = t; i < N_; i += 256) v[i] = row[i];
  __syncthreads();
  for (int it = 0; it < TOPK_; ++it){
    float bv = -3.0e38f; int bi = 0x7fffffff;
    for (int i = t; i < N_; i += 256){
      float x = v[i];
      if (x > bv){ bv = x; bi = i; }
    }
    rv[t] = bv; ri[t] = bi; __syncthreads();
    for (int s = 128; s; s >>= 1){
      if (t < s){
        float ov = rv[t + s]; int oi = ri[t + s];
        if (ov > rv[t] || (ov == rv[t] && oi < ri[t])){ rv[t] = ov; ri[t] = oi; }
      }
      __syncthreads();
    }
    if (t == 0){ idx[b * TOPK_ + it] = ri[0]; v[ri[0]] = -3.0e38f; }
    __syncthreads();
  }
}

__global__ __launch_bounds__(256)
void centroid_part(const float* __restrict__ mlps, const int* __restrict__ y,
                   const float* __restrict__ cnt, float* __restrict__ part){
  __shared__ float acc[C_ * 256];
  __shared__ float winv[C_];
  const int t  = threadIdx.x;
  const int ob = blockIdx.x * 256;
  const int e  = blockIdx.y;
  const int s  = blockIdx.z;
  #pragma unroll
  for (int c = 0; c < C_; ++c) acc[c * 256 + t] = 0.f;
  if (t < C_) winv[t] = 1.f / (cnt[t] + 1e-12f);
  __syncthreads();
  const int n0 = s * 425, n1 = n0 + 425;
  for (int n = n0; n < n1; ++n){
    int c = y[n];
    float v = mlps[((long)e * N_ + n) * D2_ + ob + t];
    acc[c * 256 + t] += winv[c] * v;
  }
  #pragma unroll
  for (int c = 0; c < C_; ++c)
    part[(((long)s * E_ + e) * C_ + c) * D2_ + ob + t] = acc[c * 256 + t];
}

__global__ __launch_bounds__(256)
void centroid_reduce(const float* __restrict__ part, float* __restrict__ cent){
  int i = blockIdx.x * 256 + threadIdx.x;
  if (i >= E_ * C_ * D2_) return;
  float s = 0.f;
  #pragma unroll
  for (int k = 0; k < 8; ++k) s += part[(long)k * E_ * C_ * D2_ + i];
  cent[i] = s;
}

__global__ __launch_bounds__(256)
void rownorm_inplace(float* __restrict__ X, int D){
  int r = blockIdx.x, t = threadIdx.x;
  float4* x4 = reinterpret_cast<float4*>(X + (long)r * D);
  float ss = 0.f;
  for (int i = t; i < (D >> 2); i += 256){
    float4 v = x4[i];
    ss += v.x*v.x + v.y*v.y + v.z*v.z + v.w*v.w;
  }
  __shared__ float red[256];
  red[t] = ss; __syncthreads();
  for (int s2 = 128; s2; s2 >>= 1){ if (t < s2) red[t] += red[t + s2]; __syncthreads(); }
  float rinv = 1.f / fmaxf(sqrtf(red[0]), 1e-12f);
  for (int i = t; i < (D >> 2); i += 256){
    float4 v = x4[i];
    v.x *= rinv; v.y *= rinv; v.z *= rinv; v.w *= rinv;
    x4[i] = v;
  }
}

// per (e,row): 17 cosine dots with cn; mode 1 -> softmax, mode 0 -> TAU*cos
__global__ __launch_bounds__(64)
void ens_dot(const float* __restrict__ mlp, const float* __restrict__ cn,
             float* __restrict__ out, int mlp_rows, int out_M, int out_rowoff, int mode){
  const int row = blockIdx.x, e = blockIdx.y, l = threadIdx.x;
  const float4* r4 = reinterpret_cast<const float4*>(mlp + ((long)e * mlp_rows + row) * D2_);
  float4 r[4];
  #pragma unroll
  for (int j = 0; j < 4; ++j) r[j] = r4[j * 64 + l];
  float ss = 0.f;
  #pragma unroll
  for (int j = 0; j < 4; ++j) ss += r[j].x*r[j].x + r[j].y*r[j].y + r[j].z*r[j].z + r[j].w*r[j].w;
  ss = wsum64(ss);
  float rinv = 1.f / fmaxf(sqrtf(ss), 1e-12f);
  float tv[C_];
  #pragma unroll
  for (int c = 0; c < C_; ++c){
    const float4* c4 = reinterpret_cast<const float4*>(cn + ((long)e * C_ + c) * D2_);
    float p = 0.f;
    #pragma unroll
    for (int j = 0; j < 4; ++j){
      float4 cv = c4[j * 64 + l];
      p += r[j].x*cv.x + r[j].y*cv.y + r[j].z*cv.z + r[j].w*cv.w;
    }
    tv[c] = wsum64(p) * rinv * TAU_;
  }
  long obase = ((long)e * out_M + out_rowoff + row) * C_;
  if (mode == 0){
    if (l == 0){
      #pragma unroll
      for (int c = 0; c < C_; ++c) out[obase + c] = tv[c];
    }
  } else {
    float m = tv[0];
    #pragma unroll
    for (int c = 1; c < C_; ++c) m = fmaxf(m, tv[c]);
    float p[C_]; float sum = 0.f;
    #pragma unroll
    for (int c = 0; c < C_; ++c){ p[c] = expf(tv[c] - m); sum += p[c]; }
    float is = 1.f / sum;
    if (l == 0){
      #pragma unroll
      for (int c = 0; c < C_; ++c) out[obase + c] = p[c] * is;
    }
  }
}

__global__ __launch_bounds__(256)
void outputs_k(const float* __restrict__ soft, const int* __restrict__ idx, float* __restrict__ out){
  const int lane = threadIdx.x & 63;
  const int b = blockIdx.x * 4 + (threadIdx.x >> 6);
  const int* id = idx + b * TOPK_;
  float o = 0.f;
  for (int e = 0; e < E_; ++e){
    float S = 0.f;
    const float* se = soft + (long)e * N_ * C_;
    #pragma unroll
    for (int k = 0; k < TOPK_; ++k){
      int n = id[k];
      if (lane < C_) S += se[(long)n * C_ + lane];
    }
    float tot = wsum64(S);
    o += S / (tot + 1e-12f);
  }
  if (lane < C_) out[(long)b * C_ + lane] = o * (1.f / E_);
}

extern "C" void kernel_launch(void* const* d_in, const int* in_sizes, int n_in,
                              void* d_out, int out_size, void* d_ws, size_t ws_size,
                              hipStream_t stream){
  const float* z        = (const float*)d_in[0];
  const float* supports = (const float*)d_in[1];
  const float* labels   = (const float*)d_in[2];
  const float* weight   = (const float*)d_in[3];
  const float* alpha    = (const float*)d_in[4];
  const float* gamma    = (const float*)d_in[5];
  const float* bias     = (const float*)d_in[6];
  float* out = (float*)d_out;

  char* w = (char*)d_ws;
  size_t off = 0;
  auto alloc = [&](size_t bytes)->char*{
    char* p = w + off;
    off = (off + bytes + 255) & ~(size_t)255;
    return p;
  };
  float* zinv   = (float*)alloc((size_t)B_ * 4);
  float* sinv   = (float*)alloc((size_t)N_ * 4);
  float* cnt    = (float*)alloc((size_t)C_ * 4);
  int*   y      = (int*)  alloc((size_t)N_ * 4);
  int*   idx    = (int*)  alloc((size_t)B_ * TOPK_ * 4);
  float* scores = (float*)alloc((size_t)B_ * N_ * 4);
  float* mlps   = (float*)alloc((size_t)E_ * N_ * D2_ * 4);
  float* part   = (float*)alloc((size_t)8 * E_ * C_ * D2_ * 4);
  float* cent   = (float*)alloc((size_t)E_ * C_ * D2_ * 4);
  float* soft   = (float*)alloc((size_t)E_ * N_ * C_ * 4);
  float* mlpz   = (float*)alloc((size_t)E_ * 1024 * D2_ * 4);
  (void)ws_size; (void)in_sizes; (void)n_in; (void)out_size;

  // row norms of z / supports (applied as post-scales in the scores GEMM)
  rownorm_inv<<<B_, 256, 0, stream>>>(z, D1_, zinv);
  rownorm_inv<<<N_, 256, 0, stream>>>(supports, D1_, sinv);

  // label prep
  zero_cnt<<<1, 32, 0, stream>>>(cnt);
  labelprep<<<(N_ + 255) / 256, 256, 0, stream>>>(labels, y, cnt);

  // cosine scores (fp32 — top-k boundary needs it) + top-20
  gemm64<<<dim3((N_ + 63) / 64, (B_ + 63) / 64, 1), 256, 0, stream>>>(
      z, D1_, supports, D1_, scores, 0, N_, B_, N_, D1_, zinv, sinv);
  topk20<<<B_, 256, 0, stream>>>(scores, idx);

  // mlp_s via bf16 MFMA
  mfma_mlp<<<dim3(D2_ / 128, (N_ + 127) / 128, E_), 256, 0, stream>>>(
      supports, weight, alpha, gamma, bias, mlps, (long)N_ * D2_, N_);

  // centroids, then L2-normalize rows
  centroid_part<<<dim3(D2_ / 256, E_, 8), 256, 0, stream>>>(mlps, y, cnt, part);
  centroid_reduce<<<(E_ * C_ * D2_ + 255) / 256, 256, 0, stream>>>(part, cent);
  rownorm_inplace<<<E_ * C_, 256, 0, stream>>>(cent, D2_);

  // soft = softmax(TAU * cos(mlp_s, cent))
  ens_dot<<<dim3(N_, E_), 64, 0, stream>>>(mlps, cent, soft, N_, N_, 0, 1);

  // outputs
  outputs_k<<<B_ / 4, 256, 0, stream>>>(soft, idx, out);

  // logits, chunked over z rows (bf16 MFMA per chunk)
  float* logits = out + (size_t)B_ * C_;
  for (int ch = 0; ch < 4; ++ch){
    mfma_mlp<<<dim3(D2_ / 128, 1024 / 128, E_), 256, 0, stream>>>(
        z + (size_t)ch * 1024 * D1_, weight, alpha, gamma, bias,
        mlpz, (long)1024 * D2_, 1024);
    ens_dot<<<dim3(1024, E_), 64, 0, stream>>>(mlpz, cent, logits, 1024, B_, ch * 1024, 0);
  }
}

// Round 3
// 1653.874 us; speedup vs baseline: 3.4446x; 1.3402x over previous
//
#include <hip/hip_runtime.h>
#include <math.h>

#define B_    4096
#define N_    3400
#define D1_   2048
#define D2_   1024
#define E_    10
#define C_    17
#define TOPK_ 20
#define TAU_  10.0f

typedef __bf16 bf16x8 __attribute__((ext_vector_type(8)));
typedef float  f32x4  __attribute__((ext_vector_type(4)));

__device__ inline float wsum64(float v){
  #pragma unroll
  for (int m = 1; m < 64; m <<= 1) v += __shfl_xor(v, m);
  return v;
}

// 8 floats -> bf16x8 (compiler emits v_cvt_pk_bf16_f32, RNE)
__device__ inline bf16x8 to_bf8(const float4& a, const float4& b){
  bf16x8 r;
  r[0]=(__bf16)a.x; r[1]=(__bf16)a.y; r[2]=(__bf16)a.z; r[3]=(__bf16)a.w;
  r[4]=(__bf16)b.x; r[5]=(__bf16)b.y; r[6]=(__bf16)b.z; r[7]=(__bf16)b.w;
  return r;
}

// split 8 floats into hi (bf16 RNE) and lo (bf16 of exact residual)
__device__ inline void split8(const float4& a, const float4& b, bf16x8& hi, bf16x8& lo){
  float f[8] = {a.x,a.y,a.z,a.w,b.x,b.y,b.z,b.w};
  #pragma unroll
  for (int i = 0; i < 8; ++i){
    __bf16 h = (__bf16)f[i];
    hi[i] = h;
    lo[i] = (__bf16)(f[i] - (float)h);
  }
}

// --- row 1/max(||x||,eps) for [R][D] ---
__global__ __launch_bounds__(256)
void rownorm_inv(const float* __restrict__ X, int D, float* __restrict__ rinv){
  int r = blockIdx.x, t = threadIdx.x;
  const float4* x4 = reinterpret_cast<const float4*>(X + (long)r * D);
  float ss = 0.f;
  for (int i = t; i < (D >> 2); i += 256){
    float4 v = x4[i];
    ss += v.x*v.x + v.y*v.y + v.z*v.z + v.w*v.w;
  }
  __shared__ float red[256];
  red[t] = ss; __syncthreads();
  for (int s = 128; s; s >>= 1){ if (t < s) red[t] += red[t + s]; __syncthreads(); }
  if (t == 0) rinv[r] = 1.f / fmaxf(sqrtf(red[0]), 1e-12f);
}

__global__ void zero_cnt(float* cnt){ if (threadIdx.x < C_) cnt[threadIdx.x] = 0.f; }

__global__ __launch_bounds__(256)
void labelprep(const float* __restrict__ labels, int* __restrict__ y, float* __restrict__ cnt){
  int n = blockIdx.x * 256 + threadIdx.x;
  if (n >= N_) return;
  int c = 0;
  #pragma unroll
  for (int cc = 0; cc < C_; ++cc) if (labels[n * C_ + cc] > 0.5f) c = cc;
  y[n] = c;
  atomicAdd(&cnt[c], 1.0f);
}

// scores[m][n] = zinv[m]*sinv[n] * ( Z[m,:]·S[n,:] )  via split-bf16 3-term MFMA
// (hi*hi + hi*lo + lo*hi; dropped lo*lo ~8e-8 on cosine — selection-safe)
__global__ __launch_bounds__(256)
void mfma_scores(const float* __restrict__ Z, const float* __restrict__ S,
                 const float* __restrict__ zinv, const float* __restrict__ sinv,
                 float* __restrict__ Out)
{
  __shared__ unsigned short Ahi[128 * 32];
  __shared__ unsigned short Alo[128 * 32];
  __shared__ unsigned short Bhi[128 * 32];
  __shared__ unsigned short Blo[128 * 32];
  const int n0 = blockIdx.x * 128;
  const int m0 = blockIdx.y * 128;
  const int t  = threadIdx.x;
  const int lane = t & 63;
  const int w  = t >> 6;
  const int wr = w >> 1, wc = w & 1;
  const int srow = t >> 1;
  const int skh  = (t & 1) * 16;
  const bool bok = (n0 + srow) < N_;
  const float* ap = Z + (long)(m0 + srow) * D1_ + skh;
  const float* bp = S + (long)(n0 + srow) * D1_ + skh;
  const unsigned sub = (srow >> 4) * 512;
  const unsigned sl0 = sub + (((skh >> 3) + 0) * 16 + (srow & 15)) * 8;
  const unsigned sl1 = sub + (((skh >> 3) + 1) * 16 + (srow & 15)) * 8;

  f32x4 acc[4][4];
  #pragma unroll
  for (int i = 0; i < 4; ++i)
    #pragma unroll
    for (int j = 0; j < 4; ++j)
      acc[i][j] = (f32x4){0.f, 0.f, 0.f, 0.f};

  for (int k0 = 0; k0 < D1_; k0 += 32){
    const float4* a4 = reinterpret_cast<const float4*>(ap + k0);
    float4 av0 = a4[0], av1 = a4[1], av2 = a4[2], av3 = a4[3];
    float4 bv0 = make_float4(0,0,0,0), bv1 = bv0, bv2 = bv0, bv3 = bv0;
    if (bok){
      const float4* b4 = reinterpret_cast<const float4*>(bp + k0);
      bv0 = b4[0]; bv1 = b4[1]; bv2 = b4[2]; bv3 = b4[3];
    }
    bf16x8 ah0, al0, ah1, al1, bh0, bl0, bh1, bl1;
    split8(av0, av1, ah0, al0); split8(av2, av3, ah1, al1);
    split8(bv0, bv1, bh0, bl0); split8(bv2, bv3, bh1, bl1);

    __syncthreads();   // prior iter's frag reads done
    *reinterpret_cast<bf16x8*>(&Ahi[sl0]) = ah0;
    *reinterpret_cast<bf16x8*>(&Ahi[sl1]) = ah1;
    *reinterpret_cast<bf16x8*>(&Alo[sl0]) = al0;
    *reinterpret_cast<bf16x8*>(&Alo[sl1]) = al1;
    *reinterpret_cast<bf16x8*>(&Bhi[sl0]) = bh0;
    *reinterpret_cast<bf16x8*>(&Bhi[sl1]) = bh1;
    *reinterpret_cast<bf16x8*>(&Blo[sl0]) = bl0;
    *reinterpret_cast<bf16x8*>(&Blo[sl1]) = bl1;
    __syncthreads();

    bf16x8 afh[4], bfh[4];
    #pragma unroll
    for (int i = 0; i < 4; ++i)
      afh[i] = *reinterpret_cast<const bf16x8*>(&Ahi[(wr*4 + i) * 512 + lane * 8]);
    #pragma unroll
    for (int j = 0; j < 4; ++j)
      bfh[j] = *reinterpret_cast<const bf16x8*>(&Bhi[(wc*4 + j) * 512 + lane * 8]);
    #pragma unroll
    for (int i = 0; i < 4; ++i)
      #pragma unroll
      for (int j = 0; j < 4; ++j)
        acc[i][j] = __builtin_amdgcn_mfma_f32_16x16x32_bf16(afh[i], bfh[j], acc[i][j], 0, 0, 0);

    bf16x8 bfl[4];
    #pragma unroll
    for (int j = 0; j < 4; ++j)
      bfl[j] = *reinterpret_cast<const bf16x8*>(&Blo[(wc*4 + j) * 512 + lane * 8]);
    #pragma unroll
    for (int i = 0; i < 4; ++i)
      #pragma unroll
      for (int j = 0; j < 4; ++j)
        acc[i][j] = __builtin_amdgcn_mfma_f32_16x16x32_bf16(afh[i], bfl[j], acc[i][j], 0, 0, 0);

    bf16x8 afl[4];
    #pragma unroll
    for (int i = 0; i < 4; ++i)
      afl[i] = *reinterpret_cast<const bf16x8*>(&Alo[(wr*4 + i) * 512 + lane * 8]);
    #pragma unroll
    for (int i = 0; i < 4; ++i)
      #pragma unroll
      for (int j = 0; j < 4; ++j)
        acc[i][j] = __builtin_amdgcn_mfma_f32_16x16x32_bf16(afl[i], bfh[j], acc[i][j], 0, 0, 0);
  }

  const int mb = m0 + wr * 64 + (lane >> 4) * 4;
  const int nb = n0 + wc * 64 + (lane & 15);
  #pragma unroll
  for (int i = 0; i < 4; ++i){
    #pragma unroll
    for (int j = 0; j < 4; ++j){
      int n = nb + j * 16;
      if (n >= N_) continue;
      float si = sinv[n];
      #pragma unroll
      for (int r = 0; r < 4; ++r){
        int m = mb + i * 16 + r;
        Out[(long)m * N_ + n] = acc[i][j][r] * zinv[m] * si;
      }
    }
  }
}

// MFMA bf16 GEMM: Out[e][m][n] = gamma[e][n]*( sum_k A[m,k]*alpha[e,k]*W[n,k] ) + bias[e][n]
__global__ __launch_bounds__(256)
void mfma_mlp(const float* __restrict__ A,
              const float* __restrict__ W,
              const float* __restrict__ alpha,
              const float* __restrict__ gamma,
              const float* __restrict__ bias,
              float* __restrict__ Out, long out_estride, int M)
{
  __shared__ unsigned short Alds[128 * 32];
  __shared__ unsigned short Blds[128 * 32];
  const int e  = blockIdx.z;
  const int n0 = blockIdx.x * 128;
  const int m0 = blockIdx.y * 128;
  const int t  = threadIdx.x;
  const int lane = t & 63;
  const int w  = t >> 6;
  const int wr = w >> 1, wc = w & 1;
  const int srow = t >> 1;
  const int skh  = (t & 1) * 16;
  const bool arowok = (m0 + srow) < M;
  const float* ap  = A + (long)(m0 + srow) * D1_ + skh;
  const float* bp  = W + (long)(n0 + srow) * D1_ + skh;
  const float* ksp = alpha + (long)e * D1_ + skh;
  const unsigned sub = (srow >> 4) * 512;
  const unsigned sl0 = sub + (((skh >> 3) + 0) * 16 + (srow & 15)) * 8;
  const unsigned sl1 = sub + (((skh >> 3) + 1) * 16 + (srow & 15)) * 8;

  f32x4 acc[4][4];
  #pragma unroll
  for (int i = 0; i < 4; ++i)
    #pragma unroll
    for (int j = 0; j < 4; ++j)
      acc[i][j] = (f32x4){0.f, 0.f, 0.f, 0.f};

  for (int k0 = 0; k0 < D1_; k0 += 32){
    float4 av0 = make_float4(0,0,0,0), av1 = av0, av2 = av0, av3 = av0;
    if (arowok){
      const float4* a4 = reinterpret_cast<const float4*>(ap + k0);
      av0 = a4[0]; av1 = a4[1]; av2 = a4[2]; av3 = a4[3];
    }
    const float4* k4 = reinterpret_cast<const float4*>(ksp + k0);
    float4 kv0 = k4[0], kv1 = k4[1], kv2 = k4[2], kv3 = k4[3];
    av0.x*=kv0.x; av0.y*=kv0.y; av0.z*=kv0.z; av0.w*=kv0.w;
    av1.x*=kv1.x; av1.y*=kv1.y; av1.z*=kv1.z; av1.w*=kv1.w;
    av2.x*=kv2.x; av2.y*=kv2.y; av2.z*=kv2.z; av2.w*=kv2.w;
    av3.x*=kv3.x; av3.y*=kv3.y; av3.z*=kv3.z; av3.w*=kv3.w;
    const float4* b4 = reinterpret_cast<const float4*>(bp + k0);
    float4 bv0 = b4[0], bv1 = b4[1], bv2 = b4[2], bv3 = b4[3];

    bf16x8 a01 = to_bf8(av0, av1), a23 = to_bf8(av2, av3);
    bf16x8 b01 = to_bf8(bv0, bv1), b23 = to_bf8(bv2, bv3);

    __syncthreads();
    *reinterpret_cast<bf16x8*>(&Alds[sl0]) = a01;
    *reinterpret_cast<bf16x8*>(&Alds[sl1]) = a23;
    *reinterpret_cast<bf16x8*>(&Blds[sl0]) = b01;
    *reinterpret_cast<bf16x8*>(&Blds[sl1]) = b23;
    __syncthreads();

    bf16x8 af[4], bf[4];
    #pragma unroll
    for (int i = 0; i < 4; ++i)
      af[i] = *reinterpret_cast<const bf16x8*>(&Alds[(wr*4 + i) * 512 + lane * 8]);
    #pragma unroll
    for (int j = 0; j < 4; ++j)
      bf[j] = *reinterpret_cast<const bf16x8*>(&Blds[(wc*4 + j) * 512 + lane * 8]);
    #pragma unroll
    for (int i = 0; i < 4; ++i)
      #pragma unroll
      for (int j = 0; j < 4; ++j)
        acc[i][j] = __builtin_amdgcn_mfma_f32_16x16x32_bf16(af[i], bf[j], acc[i][j], 0, 0, 0);
  }

  const float* cs = gamma + (long)e * D2_;
  const float* cb = bias  + (long)e * D2_;
  float* op = Out + (long)e * out_estride;
  const int mb = m0 + wr * 64 + (lane >> 4) * 4;
  const int nb = n0 + wc * 64 + (lane & 15);
  #pragma unroll
  for (int i = 0; i < 4; ++i){
    #pragma unroll
    for (int j = 0; j < 4; ++j){
      int n = nb + j * 16;
      float g = cs[n], o = cb[n];
      #pragma unroll
      for (int r = 0; r < 4; ++r){
        int m = mb + i * 16 + r;
        if (m < M) op[(long)m * D2_ + n] = acc[i][j][r] * g + o;
      }
    }
  }
}

// top-20 (value desc, tie -> lower index) per row of scores[B_][N_]
__global__ __launch_bounds__(256)
void topk20(const float* __restrict__ scores, int* __restrict__ idx){
  __shared__ float v[N_];
  __shared__ float rv[256];
  __shared__ int   ri[256];
  const int b = blockIdx.x, t = threadIdx.x;
  const float* row = scores + (long)b * N_;
  for (int i = t; i < N_; i += 256) v[i] = row[i];
  __syncthreads();
  for (int it = 0; it < TOPK_; ++it){
    float bv = -3.0e38f; int bi = 0x7fffffff;
    for (int i = t; i < N_; i += 256){
      float x = v[i];
      if (x > bv){ bv = x; bi = i; }
    }
    rv[t] = bv; ri[t] = bi; __syncthreads();
    for (int s = 128; s; s >>= 1){
      if (t < s){
        float ov = rv[t + s]; int oi = ri[t + s];
        if (ov > rv[t] || (ov == rv[t] && oi < ri[t])){ rv[t] = ov; ri[t] = oi; }
      }
      __syncthreads();
    }
    if (t == 0){ idx[b * TOPK_ + it] = ri[0]; v[ri[0]] = -3.0e38f; }
    __syncthreads();
  }
}

__global__ __launch_bounds__(256)
void centroid_part(const float* __restrict__ mlps, const int* __restrict__ y,
                   const float* __restrict__ cnt, float* __restrict__ part){
  __shared__ float acc[C_ * 256];
  __shared__ float winv[C_];
  const int t  = threadIdx.x;
  const int ob = blockIdx.x * 256;
  const int e  = blockIdx.y;
  const int s  = blockIdx.z;
  #pragma unroll
  for (int c = 0; c < C_; ++c) acc[c * 256 + t] = 0.f;
  if (t < C_) winv[t] = 1.f / (cnt[t] + 1e-12f);
  __syncthreads();
  const int n0 = s * 425, n1 = n0 + 425;
  for (int n = n0; n < n1; ++n){
    int c = y[n];
    float v = mlps[((long)e * N_ + n) * D2_ + ob + t];
    acc[c * 256 + t] += winv[c] * v;
  }
  #pragma unroll
  for (int c = 0; c < C_; ++c)
    part[(((long)s * E_ + e) * C_ + c) * D2_ + ob + t] = acc[c * 256 + t];
}

__global__ __launch_bounds__(256)
void centroid_reduce(const float* __restrict__ part, float* __restrict__ cent){
  int i = blockIdx.x * 256 + threadIdx.x;
  if (i >= E_ * C_ * D2_) return;
  float s = 0.f;
  #pragma unroll
  for (int k = 0; k < 8; ++k) s += part[(long)k * E_ * C_ * D2_ + i];
  cent[i] = s;
}

__global__ __launch_bounds__(256)
void rownorm_inplace(float* __restrict__ X, int D){
  int r = blockIdx.x, t = threadIdx.x;
  float4* x4 = reinterpret_cast<float4*>(X + (long)r * D);
  float ss = 0.f;
  for (int i = t; i < (D >> 2); i += 256){
    float4 v = x4[i];
    ss += v.x*v.x + v.y*v.y + v.z*v.z + v.w*v.w;
  }
  __shared__ float red[256];
  red[t] = ss; __syncthreads();
  for (int s2 = 128; s2; s2 >>= 1){ if (t < s2) red[t] += red[t + s2]; __syncthreads(); }
  float rinv = 1.f / fmaxf(sqrtf(red[0]), 1e-12f);
  for (int i = t; i < (D >> 2); i += 256){
    float4 v = x4[i];
    v.x *= rinv; v.y *= rinv; v.z *= rinv; v.w *= rinv;
    x4[i] = v;
  }
}

// per (e,row): 17 cosine dots with cn; mode 1 -> softmax, mode 0 -> TAU*cos
__global__ __launch_bounds__(64)
void ens_dot(const float* __restrict__ mlp, const float* __restrict__ cn,
             float* __restrict__ out, int mlp_rows, int out_M, int out_rowoff, int mode){
  const int row = blockIdx.x, e = blockIdx.y, l = threadIdx.x;
  const float4* r4 = reinterpret_cast<const float4*>(mlp + ((long)e * mlp_rows + row) * D2_);
  float4 r[4];
  #pragma unroll
  for (int j = 0; j < 4; ++j) r[j] = r4[j * 64 + l];
  float ss = 0.f;
  #pragma unroll
  for (int j = 0; j < 4; ++j) ss += r[j].x*r[j].x + r[j].y*r[j].y + r[j].z*r[j].z + r[j].w*r[j].w;
  ss = wsum64(ss);
  float rinv = 1.f / fmaxf(sqrtf(ss), 1e-12f);
  float tv[C_];
  #pragma unroll
  for (int c = 0; c < C_; ++c){
    const float4* c4 = reinterpret_cast<const float4*>(cn + ((long)e * C_ + c) * D2_);
    float p = 0.f;
    #pragma unroll
    for (int j = 0; j < 4; ++j){
      float4 cv = c4[j * 64 + l];
      p += r[j].x*cv.x + r[j].y*cv.y + r[j].z*cv.z + r[j].w*cv.w;
    }
    tv[c] = wsum64(p) * rinv * TAU_;
  }
  long obase = ((long)e * out_M + out_rowoff + row) * C_;
  if (mode == 0){
    if (l == 0){
      #pragma unroll
      for (int c = 0; c < C_; ++c) out[obase + c] = tv[c];
    }
  } else {
    float m = tv[0];
    #pragma unroll
    for (int c = 1; c < C_; ++c) m = fmaxf(m, tv[c]);
    float p[C_]; float sum = 0.f;
    #pragma unroll
    for (int c = 0; c < C_; ++c){ p[c] = expf(tv[c] - m); sum += p[c]; }
    float is = 1.f / sum;
    if (l == 0){
      #pragma unroll
      for (int c = 0; c < C_; ++c) out[obase + c] = p[c] * is;
    }
  }
}

__global__ __launch_bounds__(256)
void outputs_k(const float* __restrict__ soft, const int* __restrict__ idx, float* __restrict__ out){
  const int lane = threadIdx.x & 63;
  const int b = blockIdx.x * 4 + (threadIdx.x >> 6);
  const int* id = idx + b * TOPK_;
  float o = 0.f;
  for (int e = 0; e < E_; ++e){
    float S = 0.f;
    const float* se = soft + (long)e * N_ * C_;
    #pragma unroll
    for (int k = 0; k < TOPK_; ++k){
      int n = id[k];
      if (lane < C_) S += se[(long)n * C_ + lane];
    }
    float tot = wsum64(S);
    o += S / (tot + 1e-12f);
  }
  if (lane < C_) out[(long)b * C_ + lane] = o * (1.f / E_);
}

extern "C" void kernel_launch(void* const* d_in, const int* in_sizes, int n_in,
                              void* d_out, int out_size, void* d_ws, size_t ws_size,
                              hipStream_t stream){
  const float* z        = (const float*)d_in[0];
  const float* supports = (const float*)d_in[1];
  const float* labels   = (const float*)d_in[2];
  const float* weight   = (const float*)d_in[3];
  const float* alpha    = (const float*)d_in[4];
  const float* gamma    = (const float*)d_in[5];
  const float* bias     = (const float*)d_in[6];
  float* out = (float*)d_out;

  char* w = (char*)d_ws;
  size_t off = 0;
  auto alloc = [&](size_t bytes)->char*{
    char* p = w + off;
    off = (off + bytes + 255) & ~(size_t)255;
    return p;
  };
  float* zinv   = (float*)alloc((size_t)B_ * 4);
  float* sinv   = (float*)alloc((size_t)N_ * 4);
  float* cnt    = (float*)alloc((size_t)C_ * 4);
  int*   y      = (int*)  alloc((size_t)N_ * 4);
  int*   idx    = (int*)  alloc((size_t)B_ * TOPK_ * 4);
  float* scores = (float*)alloc((size_t)B_ * N_ * 4);
  float* mlps   = (float*)alloc((size_t)E_ * N_ * D2_ * 4);
  float* part   = (float*)alloc((size_t)8 * E_ * C_ * D2_ * 4);
  float* cent   = (float*)alloc((size_t)E_ * C_ * D2_ * 4);
  float* soft   = (float*)alloc((size_t)E_ * N_ * C_ * 4);
  float* mlpz   = (float*)alloc((size_t)E_ * 1024 * D2_ * 4);
  (void)ws_size; (void)in_sizes; (void)n_in; (void)out_size;

  // row norms of z / supports (applied as post-scales in the scores GEMM)
  rownorm_inv<<<B_, 256, 0, stream>>>(z, D1_, zinv);
  rownorm_inv<<<N_, 256, 0, stream>>>(supports, D1_, sinv);

  // label prep
  zero_cnt<<<1, 32, 0, stream>>>(cnt);
  labelprep<<<(N_ + 255) / 256, 256, 0, stream>>>(labels, y, cnt);

  // cosine scores via split-bf16 MFMA (fp32-faithful for top-k) + top-20
  mfma_scores<<<dim3((N_ + 127) / 128, B_ / 128, 1), 256, 0, stream>>>(
      z, supports, zinv, sinv, scores);
  topk20<<<B_, 256, 0, stream>>>(scores, idx);

  // mlp_s via bf16 MFMA
  mfma_mlp<<<dim3(D2_ / 128, (N_ + 127) / 128, E_), 256, 0, stream>>>(
      supports, weight, alpha, gamma, bias, mlps, (long)N_ * D2_, N_);

  // centroids, then L2-normalize rows
  centroid_part<<<dim3(D2_ / 256, E_, 8), 256, 0, stream>>>(mlps, y, cnt, part);
  centroid_reduce<<<(E_ * C_ * D2_ + 255) / 256, 256, 0, stream>>>(part, cent);
  rownorm_inplace<<<E_ * C_, 256, 0, stream>>>(cent, D2_);

  // soft = softmax(TAU * cos(mlp_s, cent))
  ens_dot<<<dim3(N_, E_), 64, 0, stream>>>(mlps, cent, soft, N_, N_, 0, 1);

  // outputs
  outputs_k<<<B_ / 4, 256, 0, stream>>>(soft, idx, out);

  // logits, chunked over z rows (bf16 MFMA per chunk)
  float* logits = out + (size_t)B_ * C_;
  for (int ch = 0; ch < 4; ++ch){
    mfma_mlp<<<dim3(D2_ / 128, 1024 / 128, E_), 256, 0, stream>>>(
        z + (size_t)ch * 1024 * D1_, weight, alpha, gamma, bias,
        mlpz, (long)1024 * D2_, 1024);
    ens_dot<<<dim3(1024, E_), 64, 0, stream>>>(mlpz, cent, logits, 1024, B_, ch * 1024, 0);
  }
}

// Round 5
// 1476.128 us; speedup vs baseline: 3.8594x; 1.1204x over previous
//
#include <hip/hip_runtime.h>
#include <math.h>

#define B_    4096
#define N_    3400
#define NP_   3456          // N_ padded to 128
#define D1_   2048
#define D2_   1024
#define E_    10
#define NE_   (E_ * D2_)    // 10240 fused ensemble columns
#define C_    17
#define TOPK_ 20
#define TAU_  10.0f

typedef __bf16 bf16x8 __attribute__((ext_vector_type(8)));
typedef __bf16 bf16x4 __attribute__((ext_vector_type(4)));
typedef float  f32x4  __attribute__((ext_vector_type(4)));

__device__ inline float wsum64(float v){
  #pragma unroll
  for (int m = 1; m < 64; m <<= 1) v += __shfl_xor(v, m);
  return v;
}

__device__ __forceinline__ void gload_lds16(const unsigned short* g, unsigned short* l){
  __builtin_amdgcn_global_load_lds(
      (const __attribute__((address_space(1))) void*)g,
      (__attribute__((address_space(3))) void*)l, 16, 0, 0);
}

// --- row 1/max(||x||,eps) for [R][D] ---
__global__ __launch_bounds__(256)
void rownorm_inv(const float* __restrict__ X, int D, float* __restrict__ rinv){
  int r = blockIdx.x, t = threadIdx.x;
  const float4* x4 = reinterpret_cast<const float4*>(X + (long)r * D);
  float ss = 0.f;
  for (int i = t; i < (D >> 2); i += 256){
    float4 v = x4[i];
    ss += v.x*v.x + v.y*v.y + v.z*v.z + v.w*v.w;
  }
  __shared__ float red[256];
  red[t] = ss; __syncthreads();
  for (int s = 128; s; s >>= 1){ if (t < s) red[t] += red[t + s]; __syncthreads(); }
  if (t == 0) rinv[r] = 1.f / fmaxf(sqrtf(red[0]), 1e-12f);
}

__global__ void zero_cnt(float* cnt){ if (threadIdx.x < C_) cnt[threadIdx.x] = 0.f; }

__global__ __launch_bounds__(256)
void labelprep(const float* __restrict__ labels, int* __restrict__ y, float* __restrict__ cnt){
  int n = blockIdx.x * 256 + threadIdx.x;
  if (n >= N_) return;
  int c = 0;
  #pragma unroll
  for (int cc = 0; cc < C_; ++cc) if (labels[n * C_ + cc] > 0.5f) c = cc;
  y[n] = c;
  atomicAdd(&cnt[c], 1.0f);
}

// fp32 -> (hi bf16, lo bf16 of exact residual), 4 elems/thread
__global__ __launch_bounds__(256)
void cvt_split(const float* __restrict__ src, unsigned short* __restrict__ hi,
               unsigned short* __restrict__ lo, long n4){
  long i = (long)blockIdx.x * 256 + threadIdx.x;
  if (i >= n4) return;
  float4 v = reinterpret_cast<const float4*>(src)[i];
  float f[4] = {v.x, v.y, v.z, v.w};
  bf16x4 h4, l4;
  #pragma unroll
  for (int j = 0; j < 4; ++j){
    __bf16 h = (__bf16)f[j];
    h4[j] = h;
    l4[j] = (__bf16)(f[j] - (float)h);
  }
  reinterpret_cast<bf16x4*>(hi)[i] = h4;
  reinterpret_cast<bf16x4*>(lo)[i] = l4;
}

// zero-fill pad rows [N_, NP_) of two bf16 [NP_][D1_] arrays (16B stores)
__global__ __launch_bounds__(256)
void fill_pad(unsigned short* __restrict__ a, unsigned short* __restrict__ b){
  int i = blockIdx.x * 256 + threadIdx.x;   // 16B units; total (NP_-N_)*D1_/8 = 14336
  uint4 zz = make_uint4(0,0,0,0);
  reinterpret_cast<uint4*>(a + (long)N_ * D1_)[i] = zz;
  reinterpret_cast<uint4*>(b + (long)N_ * D1_)[i] = zz;
}

// Wbf[e][n][k] = bf16(alpha[e][k] * W[n][k]),  laid out [NE_][D1_]
__global__ __launch_bounds__(256)
void wfold(const float* __restrict__ W, const float* __restrict__ alpha,
           unsigned short* __restrict__ wbf){
  long i = (long)blockIdx.x * 256 + threadIdx.x;       // float4 units
  const long perE = (long)D2_ * D1_ / 4;               // 524288
  int e = (int)(i / perE);
  long r = i - (long)e * perE;
  int k4 = (int)(r & (D1_/4 - 1));
  float4 wv = reinterpret_cast<const float4*>(W)[r];
  float4 av = reinterpret_cast<const float4*>(alpha + (long)e * D1_)[k4];
  bf16x4 o;
  o[0] = (__bf16)(wv.x * av.x);
  o[1] = (__bf16)(wv.y * av.y);
  o[2] = (__bf16)(wv.z * av.z);
  o[3] = (__bf16)(wv.w * av.w);
  reinterpret_cast<bf16x4*>(wbf)[i] = o;
}

// Fused BatchEnsemble GEMM, bf16 inputs, global_load_lds staging.
// A [Mpad][D1_] bf16, Bw [NE_][D1_] bf16 (alpha-folded W).
// Out[e][m][ncol] = acc * gamma[n'] + bias[n'],  n' = e*1024+ncol.
__global__ __launch_bounds__(256)
void mfma_be(const unsigned short* __restrict__ A,
             const unsigned short* __restrict__ Bw,
             const float* __restrict__ gamma,   // [NE_]
             const float* __restrict__ bias,    // [NE_]
             float* __restrict__ Out, long estride, int M)
{
  __shared__ unsigned short Alds[128 * 32];
  __shared__ unsigned short Blds[128 * 32];
  const int n0 = blockIdx.x * 128;
  const int m0 = blockIdx.y * 128;
  const int t  = threadIdx.x;
  const int lane = t & 63;
  const int w  = t >> 6;
  const int wr = w >> 1, wc = w & 1;
  const int r15 = lane & 15, kb = lane >> 4;

  // wave w stages subtiles {2w, 2w+1}; lane l -> row (l&15), k-block (l>>4)
  const unsigned short* ga0 = A  + (long)(m0 + 32*w      + r15) * D1_ + kb * 8;
  const unsigned short* ga1 = A  + (long)(m0 + 32*w + 16 + r15) * D1_ + kb * 8;
  const unsigned short* gb0 = Bw + (long)(n0 + 32*w      + r15) * D1_ + kb * 8;
  const unsigned short* gb1 = Bw + (long)(n0 + 32*w + 16 + r15) * D1_ + kb * 8;
  unsigned short* la0 = &Alds[(2*w)   * 512];
  unsigned short* la1 = &Alds[(2*w+1) * 512];
  unsigned short* lb0 = &Blds[(2*w)   * 512];
  unsigned short* lb1 = &Blds[(2*w+1) * 512];

  f32x4 acc[4][4];
  #pragma unroll
  for (int i = 0; i < 4; ++i)
    #pragma unroll
    for (int j = 0; j < 4; ++j)
      acc[i][j] = (f32x4){0.f, 0.f, 0.f, 0.f};

  for (int k0 = 0; k0 < D1_; k0 += 32){
    __syncthreads();                   // prior ds_reads done before overwrite
    gload_lds16(ga0 + k0, la0);
    gload_lds16(ga1 + k0, la1);
    gload_lds16(gb0 + k0, lb0);
    gload_lds16(gb1 + k0, lb1);
    __syncthreads();                   // vmcnt(0) drain before reads

    bf16x8 af[4], bf[4];
    #pragma unroll
    for (int i = 0; i < 4; ++i)
      af[i] = *reinterpret_cast<const bf16x8*>(&Alds[(wr*4 + i) * 512 + lane * 8]);
    #pragma unroll
    for (int j = 0; j < 4; ++j)
      bf[j] = *reinterpret_cast<const bf16x8*>(&Blds[(wc*4 + j) * 512 + lane * 8]);
    #pragma unroll
    for (int i = 0; i < 4; ++i)
      #pragma unroll
      for (int j = 0; j < 4; ++j)
        acc[i][j] = __builtin_amdgcn_mfma_f32_16x16x32_bf16(af[i], bf[j], acc[i][j], 0, 0, 0);
  }

  const int mb = m0 + wr * 64 + (lane >> 4) * 4;
  const int nbase = n0 + wc * 64 + (lane & 15);
  #pragma unroll
  for (int j = 0; j < 4; ++j){
    int n = nbase + j * 16;            // fused column in [0, NE_)
    int e = n >> 10, ncol = n & 1023;
    float g = gamma[n], o = bias[n];
    float* op = Out + (long)e * estride;
    #pragma unroll
    for (int i = 0; i < 4; ++i){
      #pragma unroll
      for (int r = 0; r < 4; ++r){
        int m = mb + i * 16 + r;
        if (m < M) op[(long)m * D2_ + ncol] = acc[i][j][r] * g + o;
      }
    }
  }
}

// scores[m][n] = zinv[m]*sinv[n]*(Z·S) via split-bf16 3-term MFMA, gload-staged
__global__ __launch_bounds__(256)
void mfma_scores2(const unsigned short* __restrict__ zh, const unsigned short* __restrict__ zl,
                  const unsigned short* __restrict__ sh, const unsigned short* __restrict__ sl,
                  const float* __restrict__ zinv, const float* __restrict__ sinv,
                  float* __restrict__ Out)
{
  __shared__ unsigned short Ah[128 * 32];
  __shared__ unsigned short Al[128 * 32];
  __shared__ unsigned short Bh[128 * 32];
  __shared__ unsigned short Bl[128 * 32];
  const int n0 = blockIdx.x * 128;
  const int m0 = blockIdx.y * 128;
  const int t  = threadIdx.x;
  const int lane = t & 63;
  const int w  = t >> 6;
  const int wr = w >> 1, wc = w & 1;
  const int r15 = lane & 15, kb = lane >> 4;

  const long arow0 = (long)(m0 + 32*w      + r15) * D1_ + kb * 8;
  const long arow1 = (long)(m0 + 32*w + 16 + r15) * D1_ + kb * 8;
  const long brow0 = (long)(n0 + 32*w      + r15) * D1_ + kb * 8;
  const long brow1 = (long)(n0 + 32*w + 16 + r15) * D1_ + kb * 8;
  const unsigned s0 = (2*w) * 512, s1 = (2*w+1) * 512;

  f32x4 acc[4][4];
  #pragma unroll
  for (int i = 0; i < 4; ++i)
    #pragma unroll
    for (int j = 0; j < 4; ++j)
      acc[i][j] = (f32x4){0.f, 0.f, 0.f, 0.f};

  for (int k0 = 0; k0 < D1_; k0 += 32){
    __syncthreads();
    gload_lds16(zh + arow0 + k0, &Ah[s0]);
    gload_lds16(zh + arow1 + k0, &Ah[s1]);
    gload_lds16(zl + arow0 + k0, &Al[s0]);
    gload_lds16(zl + arow1 + k0, &Al[s1]);
    gload_lds16(sh + brow0 + k0, &Bh[s0]);
    gload_lds16(sh + brow1 + k0, &Bh[s1]);
    gload_lds16(sl + brow0 + k0, &Bl[s0]);
    gload_lds16(sl + brow1 + k0, &Bl[s1]);
    __syncthreads();

    bf16x8 afh[4], bfh[4];
    #pragma unroll
    for (int i = 0; i < 4; ++i)
      afh[i] = *reinterpret_cast<const bf16x8*>(&Ah[(wr*4 + i) * 512 + lane * 8]);
    #pragma unroll
    for (int j = 0; j < 4; ++j)
      bfh[j] = *reinterpret_cast<const bf16x8*>(&Bh[(wc*4 + j) * 512 + lane * 8]);
    #pragma unroll
    for (int i = 0; i < 4; ++i)
      #pragma unroll
      for (int j = 0; j < 4; ++j)
        acc[i][j] = __builtin_amdgcn_mfma_f32_16x16x32_bf16(afh[i], bfh[j], acc[i][j], 0, 0, 0);

    bf16x8 bfl[4];
    #pragma unroll
    for (int j = 0; j < 4; ++j)
      bfl[j] = *reinterpret_cast<const bf16x8*>(&Bl[(wc*4 + j) * 512 + lane * 8]);
    #pragma unroll
    for (int i = 0; i < 4; ++i)
      #pragma unroll
      for (int j = 0; j < 4; ++j)
        acc[i][j] = __builtin_amdgcn_mfma_f32_16x16x32_bf16(afh[i], bfl[j], acc[i][j], 0, 0, 0);

    bf16x8 afl[4];
    #pragma unroll
    for (int i = 0; i < 4; ++i)
      afl[i] = *reinterpret_cast<const bf16x8*>(&Al[(wr*4 + i) * 512 + lane * 8]);
    #pragma unroll
    for (int i = 0; i < 4; ++i)
      #pragma unroll
      for (int j = 0; j < 4; ++j)
        acc[i][j] = __builtin_amdgcn_mfma_f32_16x16x32_bf16(afl[i], bfh[j], acc[i][j], 0, 0, 0);
  }

  const int mb = m0 + wr * 64 + (lane >> 4) * 4;
  const int nb = n0 + wc * 64 + (lane & 15);
  #pragma unroll
  for (int j = 0; j < 4; ++j){
    int n = nb + j * 16;
    if (n >= N_) continue;
    float si = sinv[n];
    #pragma unroll
    for (int i = 0; i < 4; ++i){
      #pragma unroll
      for (int r = 0; r < 4; ++r){
        int m = mb + i * 16 + r;
        Out[(long)m * N_ + n] = acc[i][j][r] * zinv[m] * si;
      }
    }
  }
}

// top-20 (value desc, tie -> lower index) per row of scores[B_][N_]
__global__ __launch_bounds__(256)
void topk20(const float* __restrict__ scores, int* __restrict__ idx){
  __shared__ float v[N_];
  __shared__ float rv[256];
  __shared__ int   ri[256];
  const int b = blockIdx.x, t = threadIdx.x;
  const float* row = scores + (long)b * N_;
  for (int i = t; i < N_; i += 256) v[i] = row[i];
  __syncthreads();
  for (int it = 0; it < TOPK_; ++it){
    float bv = -3.0e38f; int bi = 0x7fffffff;
    for (int i = t; i < N_; i += 256){
      float x = v[i];
      if (x > bv){ bv = x; bi = i; }
    }
    rv[t] = bv; ri[t] = bi; __syncthreads();
    for (int s = 128; s; s >>= 1){
      if (t < s){
        float ov = rv[t + s]; int oi = ri[t + s];
        if (ov > rv[t] || (ov == rv[t] && oi < ri[t])){ rv[t] = ov; ri[t] = oi; }
      }
      __syncthreads();
    }
    if (t == 0){ idx[b * TOPK_ + it] = ri[0]; v[ri[0]] = -3.0e38f; }
    __syncthreads();
  }
}

__global__ __launch_bounds__(256)
void centroid_part(const float* __restrict__ mlps, const int* __restrict__ y,
                   const float* __restrict__ cnt, float* __restrict__ part){
  __shared__ float acc[C_ * 256];
  __shared__ float winv[C_];
  const int t  = threadIdx.x;
  const int ob = blockIdx.x * 256;
  const int e  = blockIdx.y;
  const int s  = blockIdx.z;
  #pragma unroll
  for (int c = 0; c < C_; ++c) acc[c * 256 + t] = 0.f;
  if (t < C_) winv[t] = 1.f / (cnt[t] + 1e-12f);
  __syncthreads();
  const int n0 = s * 425, n1 = n0 + 425;
  for (int n = n0; n < n1; ++n){
    int c = y[n];
    float v = mlps[((long)e * N_ + n) * D2_ + ob + t];
    acc[c * 256 + t] += winv[c] * v;
  }
  #pragma unroll
  for (int c = 0; c < C_; ++c)
    part[(((long)s * E_ + e) * C_ + c) * D2_ + ob + t] = acc[c * 256 + t];
}

__global__ __launch_bounds__(256)
void centroid_reduce(const float* __restrict__ part, float* __restrict__ cent){
  int i = blockIdx.x * 256 + threadIdx.x;
  if (i >= E_ * C_ * D2_) return;
  float s = 0.f;
  #pragma unroll
  for (int k = 0; k < 8; ++k) s += part[(long)k * E_ * C_ * D2_ + i];
  cent[i] = s;
}

__global__ __launch_bounds__(256)
void rownorm_inplace(float* __restrict__ X, int D){
  int r = blockIdx.x, t = threadIdx.x;
  float4* x4 = reinterpret_cast<float4*>(X + (long)r * D);
  float ss = 0.f;
  for (int i = t; i < (D >> 2); i += 256){
    float4 v = x4[i];
    ss += v.x*v.x + v.y*v.y + v.z*v.z + v.w*v.w;
  }
  __shared__ float red[256];
  red[t] = ss; __syncthreads();
  for (int s2 = 128; s2; s2 >>= 1){ if (t < s2) red[t] += red[t + s2]; __syncthreads(); }
  float rinv = 1.f / fmaxf(sqrtf(red[0]), 1e-12f);
  for (int i = t; i < (D >> 2); i += 256){
    float4 v = x4[i];
    v.x *= rinv; v.y *= rinv; v.z *= rinv; v.w *= rinv;
    x4[i] = v;
  }
}

// per (e,row): 17 cosine dots with cn; mode 1 -> softmax, mode 0 -> TAU*cos
__global__ __launch_bounds__(64)
void ens_dot(const float* __restrict__ mlp, const float* __restrict__ cn,
             float* __restrict__ out, int mlp_rows, int out_M, int out_rowoff, int mode){
  const int row = blockIdx.x, e = blockIdx.y, l = threadIdx.x;
  const float4* r4 = reinterpret_cast<const float4*>(mlp + ((long)e * mlp_rows + row) * D2_);
  float4 r[4];
  #pragma unroll
  for (int j = 0; j < 4; ++j) r[j] = r4[j * 64 + l];
  float ss = 0.f;
  #pragma unroll
  for (int j = 0; j < 4; ++j) ss += r[j].x*r[j].x + r[j].y*r[j].y + r[j].z*r[j].z + r[j].w*r[j].w;
  ss = wsum64(ss);
  float rinv = 1.f / fmaxf(sqrtf(ss), 1e-12f);
  float tv[C_];
  #pragma unroll
  for (int c = 0; c < C_; ++c){
    const float4* c4 = reinterpret_cast<const float4*>(cn + ((long)e * C_ + c) * D2_);
    float p = 0.f;
    #pragma unroll
    for (int j = 0; j < 4; ++j){
      float4 cv = c4[j * 64 + l];
      p += r[j].x*cv.x + r[j].y*cv.y + r[j].z*cv.z + r[j].w*cv.w;
    }
    tv[c] = wsum64(p) * rinv * TAU_;
  }
  long obase = ((long)e * out_M + out_rowoff + row) * C_;
  if (mode == 0){
    if (l == 0){
      #pragma unroll
      for (int c = 0; c < C_; ++c) out[obase + c] = tv[c];
    }
  } else {
    float m = tv[0];
    #pragma unroll
    for (int c = 1; c < C_; ++c) m = fmaxf(m, tv[c]);
    float p[C_]; float sum = 0.f;
    #pragma unroll
    for (int c = 0; c < C_; ++c){ p[c] = expf(tv[c] - m); sum += p[c]; }
    float is = 1.f / sum;
    if (l == 0){
      #pragma unroll
      for (int c = 0; c < C_; ++c) out[obase + c] = p[c] * is;
    }
  }
}

__global__ __launch_bounds__(256)
void outputs_k(const float* __restrict__ soft, const int* __restrict__ idx, float* __restrict__ out){
  const int lane = threadIdx.x & 63;
  const int b = blockIdx.x * 4 + (threadIdx.x >> 6);
  const int* id = idx + b * TOPK_;
  float o = 0.f;
  for (int e = 0; e < E_; ++e){
    float S = 0.f;
    const float* se = soft + (long)e * N_ * C_;
    #pragma unroll
    for (int k = 0; k < TOPK_; ++k){
      int n = id[k];
      if (lane < C_) S += se[(long)n * C_ + lane];
    }
    float tot = wsum64(S);
    o += S / (tot + 1e-12f);
  }
  if (lane < C_) out[(long)b * C_ + lane] = o * (1.f / E_);
}

extern "C" void kernel_launch(void* const* d_in, const int* in_sizes, int n_in,
                              void* d_out, int out_size, void* d_ws, size_t ws_size,
                              hipStream_t stream){
  const float* z        = (const float*)d_in[0];
  const float* supports = (const float*)d_in[1];
  const float* labels   = (const float*)d_in[2];
  const float* weight   = (const float*)d_in[3];
  const float* alpha    = (const float*)d_in[4];
  const float* gamma    = (const float*)d_in[5];
  const float* bias     = (const float*)d_in[6];
  float* out = (float*)d_out;

  char* w = (char*)d_ws;
  size_t off = 0;
  auto alloc = [&](size_t bytes)->char*{
    char* p = w + off;
    off = (off + bytes + 255) & ~(size_t)255;
    return p;
  };
  auto rup = [](size_t b)->size_t{ return (b + 255) & ~(size_t)255; };

  // ---- permanent region (~82 MB) ----
  float* zinv   = (float*)alloc((size_t)B_ * 4);
  float* sinv   = (float*)alloc((size_t)N_ * 4);
  float* cnt    = (float*)alloc((size_t)C_ * 4);
  int*   y      = (int*)  alloc((size_t)N_ * 4);
  int*   idx    = (int*)  alloc((size_t)B_ * TOPK_ * 4);
  unsigned short* zh  = (unsigned short*)alloc((size_t)B_  * D1_ * 2);
  unsigned short* sh  = (unsigned short*)alloc((size_t)NP_ * D1_ * 2);
  unsigned short* wbf = (unsigned short*)alloc((size_t)NE_ * D1_ * 2);
  float* cent = (float*)alloc((size_t)E_ * C_ * D2_ * 4);
  float* part = (float*)alloc((size_t)8 * E_ * C_ * D2_ * 4);
  float* soft = (float*)alloc((size_t)E_ * N_ * C_ * 4);

  // ---- overlay region: lifetimes do not overlap (≈139 MB) ----
  // phase 1 (scores+topk): scores | zl | sl      (86.7 MB)
  // phase 2 (mlp_s..soft): mlps                  (139.3 MB)
  // phase 3 (logits):      mlpz (aliases mlps)   (41.9 MB)
  const size_t scores_b = (size_t)B_ * N_ * 4;
  const size_t zl_b     = (size_t)B_  * D1_ * 2;
  const size_t sl_b     = (size_t)NP_ * D1_ * 2;
  const size_t mlps_b   = (size_t)E_ * N_ * D2_ * 4;
  size_t ph1 = rup(scores_b) + rup(zl_b) + rup(sl_b);
  char* overlay = alloc(ph1 > mlps_b ? ph1 : mlps_b);
  float*          scores = (float*)overlay;
  unsigned short* zl     = (unsigned short*)(overlay + rup(scores_b));
  unsigned short* sl     = (unsigned short*)(overlay + rup(scores_b) + rup(zl_b));
  float*          mlps   = (float*)overlay;          // after topk20
  float*          mlpz   = (float*)overlay;          // after ens_dot(soft)
  (void)ws_size; (void)in_sizes; (void)n_in; (void)out_size;

  // row norms + label prep
  rownorm_inv<<<B_, 256, 0, stream>>>(z, D1_, zinv);
  rownorm_inv<<<N_, 256, 0, stream>>>(supports, D1_, sinv);
  zero_cnt<<<1, 32, 0, stream>>>(cnt);
  labelprep<<<(N_ + 255) / 256, 256, 0, stream>>>(labels, y, cnt);

  // bf16 precompute: hi/lo splits (hi doubles as the mlp A operand), pad, folded W
  cvt_split<<<(B_ * D1_ / 4 + 255) / 256, 256, 0, stream>>>(z, zh, zl, (long)B_ * D1_ / 4);
  cvt_split<<<(N_ * D1_ / 4 + 255) / 256, 256, 0, stream>>>(supports, sh, sl, (long)N_ * D1_ / 4);
  fill_pad<<<(NP_ - N_) * D1_ / 8 / 256, 256, 0, stream>>>(sh, sl);
  wfold<<<(int)((long)NE_ * D1_ / 4 / 256), 256, 0, stream>>>(weight, alpha, wbf);

  // cosine scores (split-bf16 3-term, fp32-faithful for top-k) + top-20
  mfma_scores2<<<dim3(NP_ / 128, B_ / 128, 1), 256, 0, stream>>>(
      zh, zl, sh, sl, zinv, sinv, scores);
  topk20<<<B_, 256, 0, stream>>>(scores, idx);
  // (scores, zl, sl dead from here)

  // mlp_s: single fused GEMM over N' = E*D2 columns
  mfma_be<<<dim3(NE_ / 128, NP_ / 128, 1), 256, 0, stream>>>(
      sh, wbf, gamma, bias, mlps, (long)N_ * D2_, N_);

  // centroids, then L2-normalize rows
  centroid_part<<<dim3(D2_ / 256, E_, 8), 256, 0, stream>>>(mlps, y, cnt, part);
  centroid_reduce<<<(E_ * C_ * D2_ + 255) / 256, 256, 0, stream>>>(part, cent);
  rownorm_inplace<<<E_ * C_, 256, 0, stream>>>(cent, D2_);

  // soft = softmax(TAU * cos(mlp_s, cent))
  ens_dot<<<dim3(N_, E_), 64, 0, stream>>>(mlps, cent, soft, N_, N_, 0, 1);

  // outputs
  outputs_k<<<B_ / 4, 256, 0, stream>>>(soft, idx, out);
  // (mlps dead from here; mlpz reuses its space)

  // logits, chunked over z rows
  float* logits = out + (size_t)B_ * C_;
  for (int ch = 0; ch < 4; ++ch){
    mfma_be<<<dim3(NE_ / 128, 1024 / 128, 1), 256, 0, stream>>>(
        zh + (size_t)ch * 1024 * D1_, wbf, gamma, bias, mlpz, (long)1024 * D2_, 1024);
    ens_dot<<<dim3(1024, E_), 64, 0, stream>>>(mlpz, cent, logits, 1024, B_, ch * 1024, 0);
  }
}